// Round 13
// baseline (446.624 us; speedup 1.0000x reference)
//
#include <hip/hip_runtime.h>
#include <hip/hip_bf16.h>
#include <cmath>

// Problem constants
#define NVOC 100
#define DIMN 200
#define LDX  232      // xHi/xLo stride (bf16 elems)
#define LDHT 40       // hvT stride (bf16): hvT[c][j], j=0..31
#define LDMA 40       // MA stride (bf16): MA[r][j]
#define DPD  204
#define LDM  36
#define NTOT 8192
#define KP   224      // K padded to 7*32
#define NP   208      // N padded to 13*16
#define WHALF (NP*KP)
#define WL    (2*WHALF)
// grid = 256 (1 block/CU), block = 832 = 13 waves. Whole layer pipeline stays
// in MFMA C-layout registers (row=q*4+i, col=16w+ml): GEMM -> combine(regs) ->
// hvT write -> P MFMA -> x=hv+P (regs) -> bf16 split writes. 2 barriers/layer.
// bufS/bufA eliminated; norm via shuffle + ds_add into double-buffered scaleSum.

typedef __attribute__((ext_vector_type(8))) short short8_t;
typedef __attribute__((ext_vector_type(4))) short short4_t;
typedef __attribute__((ext_vector_type(4))) float f32x4;

__device__ __forceinline__ short f2bf(float v) {
    __hip_bfloat16 h = __float2bfloat16(v);
    return *reinterpret_cast<short*>(&h);
}
__device__ __forceinline__ float bf2f(short s) {
    __hip_bfloat16 h = *reinterpret_cast<__hip_bfloat16*>(&s);
    return __bfloat162float(h);
}

// ---- W conversion pre-pass: fp32 [k][n] -> bf16 hi/lo [n][k], padded ----
__global__ void conv_kernel(const float* __restrict__ Waw,
                            const float* __restrict__ Wow,
                            short* __restrict__ W2)
{
    const int total = 9 * NP * KP;
    for (int idx = blockIdx.x * 256 + threadIdx.x; idx < total;
         idx += gridDim.x * 256) {
        const int l = idx / (NP*KP);
        const int rem = idx % (NP*KP);
        const int n = rem / KP;
        const int k = rem % KP;
        float v = 0.f;
        if (n < DIMN && k < DIMN)
            v = (l < 6) ? Waw[l*40000 + k*DIMN + n]
                        : Wow[(l-6)*40000 + k*DIMN + n];
        const short hi = f2bf(v);
        const short lo = f2bf(v - bf2f(hi));
        W2[(size_t)l*WL + n*KP + k]         = hi;
        W2[(size_t)l*WL + WHALF + n*KP + k] = lo;
    }
}

// MFMA GEMM: wave w computes cols 16w..16w+15, both 16-row M-tiles, full K.
__device__ __forceinline__ void gemm_mfma(const short* __restrict__ xHi,
                                          const short* __restrict__ xLo,
                                          const short* __restrict__ Wl,
                                          int w, int lane, f32x4 acc[2])
{
    acc[0] = (f32x4){0.f,0.f,0.f,0.f};
    acc[1] = (f32x4){0.f,0.f,0.f,0.f};
    const int m = lane & 15;
    const int q = lane >> 4;
    const short* aH0 = xHi + m*LDX + q*8;
    const short* aL0 = xLo + m*LDX + q*8;
    const short* aH1 = aH0 + 16*LDX;
    const short* aL1 = aL0 + 16*LDX;
    const short* bH  = Wl + (w*16 + m)*KP + q*8;
    const short* bL  = bH + WHALF;
    #pragma unroll
    for (int ks = 0; ks < 7; ++ks) {
        const int ko = ks * 32;
        const short8_t ah0 = *(const short8_t*)(aH0 + ko);
        const short8_t al0 = *(const short8_t*)(aL0 + ko);
        const short8_t ah1 = *(const short8_t*)(aH1 + ko);
        const short8_t al1 = *(const short8_t*)(aL1 + ko);
        const short8_t bh  = *(const short8_t*)(bH + ko);
        const short8_t bl  = *(const short8_t*)(bL + ko);
        acc[0] = __builtin_amdgcn_mfma_f32_16x16x32_bf16(ah0, bh, acc[0], 0,0,0);
        acc[0] = __builtin_amdgcn_mfma_f32_16x16x32_bf16(ah0, bl, acc[0], 0,0,0);
        acc[0] = __builtin_amdgcn_mfma_f32_16x16x32_bf16(al0, bh, acc[0], 0,0,0);
        acc[1] = __builtin_amdgcn_mfma_f32_16x16x32_bf16(ah1, bh, acc[1], 0,0,0);
        acc[1] = __builtin_amdgcn_mfma_f32_16x16x32_bf16(ah1, bl, acc[1], 0,0,0);
        acc[1] = __builtin_amdgcn_mfma_f32_16x16x32_bf16(al1, bh, acc[1], 0,0,0);
    }
}

__global__ __launch_bounds__(832)
void mgnn_kernel(const int*   __restrict__ atoms,
                 const float* __restrict__ dist,
                 const float* __restrict__ adducts,
                 const float* __restrict__ embed,
                 const float* __restrict__ gamma_tab,
                 const float* __restrict__ Waw,
                 const float* __restrict__ Wab,
                 const float* __restrict__ Wow,
                 const float* __restrict__ Wob,
                 const float* __restrict__ Wpw,
                 const float* __restrict__ Wpb,
                 const float* __restrict__ Wprw,
                 const float* __restrict__ Wprb,
                 const short* __restrict__ W2,
                 float* __restrict__ out)
{
    __shared__ short xHi[32*LDX];      // x high bf16
    __shared__ short xLo[32*LDX];      // x low  bf16
    __shared__ short hvThi[NP*LDHT];   // hv^T high (B-layout for P)
    __shared__ short hvTlo[NP*LDHT];
    __shared__ short MAhi[32*LDMA];    // M high (A-layout)
    __shared__ short MAlo[32*LDMA];
    __shared__ float d2s[32*LDM];      // d^2; later reused as mv buffers
    __shared__ float scaleSum[2][32];  // double-buffered row sum-of-squares
    __shared__ float red16[16];
    __shared__ int   atom_s[32];
    // total ~75 KB

    const int mol  = blockIdx.x;
    const int t    = threadIdx.x;
    const int base = mol * 32;
    const int w    = t >> 6;          // wave 0..12 = ntile
    const int lane = t & 63;
    const int ml   = lane & 15;
    const int q    = lane >> 4;
    const int col  = 16*w + ml;       // this lane's output column (C-layout)
    const bool colok = (col < DIMN);

    // ---- init ----
    if (t < 32) atom_s[t] = atoms[base + t];
    if (t < 32)            scaleSum[0][t] = 0.f;
    else if (t < 64)       scaleSum[1][t-32] = 0.f;
    if (t < 512) {
        const int j  = t >> 4;
        const int c2 = (t & 15) * 2;
        const float2 dd = *(const float2*)&dist[(size_t)(base + j) * NTOT + base + c2];
        d2s[j*LDM + c2]     = dd.x * dd.x;
        d2s[j*LDM + c2 + 1] = dd.y * dd.y;
    }
    for (int idx = t; idx < 32*DIMN; idx += 832) {   // x0 = embed[atoms], split
        const int r = idx / DIMN, c = idx % DIMN;
        const float v = embed[atoms[base + r]*DIMN + c];
        const short hi = f2bf(v);
        xHi[r*LDX + c] = hi;
        xLo[r*LDX + c] = f2bf(v - bf2f(hi));
    }
    for (int idx = t; idx < 32*32; idx += 832) {     // zero k-pad 200..231
        const int r = idx >> 5, c = DIMN + (idx & 31);
        xHi[r*LDX + c] = 0;
        xLo[r*LDX + c] = 0;
    }
    __syncthreads();

    // ---- 6 hidden layers (2 barriers each) ----
    for (int l = 0; l < 6; ++l) {
        f32x4 macc[2];
        gemm_mfma(xHi, xLo, W2 + (size_t)l*WL, w, lane, macc);

        // combine in C-layout registers: hv = relu(sum * s_prev + b)
        float sc0[4], sc1[4];
        if (l == 0) {
            #pragma unroll
            for (int i = 0; i < 4; ++i) { sc0[i] = 1.f; sc1[i] = 1.f; }
        } else {
            const float* sb = scaleSum[(l-1)&1];
            const float4 ss0 = *(const float4*)&sb[q*4];
            const float4 ss1 = *(const float4*)&sb[16 + q*4];
            sc0[0]=1.0f/fmaxf(sqrtf(ss0.x),1e-12f); sc0[1]=1.0f/fmaxf(sqrtf(ss0.y),1e-12f);
            sc0[2]=1.0f/fmaxf(sqrtf(ss0.z),1e-12f); sc0[3]=1.0f/fmaxf(sqrtf(ss0.w),1e-12f);
            sc1[0]=1.0f/fmaxf(sqrtf(ss1.x),1e-12f); sc1[1]=1.0f/fmaxf(sqrtf(ss1.y),1e-12f);
            sc1[2]=1.0f/fmaxf(sqrtf(ss1.z),1e-12f); sc1[3]=1.0f/fmaxf(sqrtf(ss1.w),1e-12f);
        }
        const float bias = colok ? Wab[l*DIMN + col] : 0.f;
        float hv0[4], hv1[4];
        #pragma unroll
        for (int i = 0; i < 4; ++i) {
            hv0[i] = fmaxf(fmaf(macc[0][i], sc0[i], bias), 0.f);
            hv1[i] = fmaxf(fmaf(macc[1][i], sc1[i], bias), 0.f);
        }
        // hvT[col][j] bf16 hi/lo (B-operand layout for P); rows>=200 are 0
        {
            short4_t hh0, hl0, hh1, hl1;
            #pragma unroll
            for (int i = 0; i < 4; ++i) {
                const short a = f2bf(hv0[i]); hh0[i] = a; hl0[i] = f2bf(hv0[i] - bf2f(a));
                const short b = f2bf(hv1[i]); hh1[i] = b; hl1[i] = f2bf(hv1[i] - bf2f(b));
            }
            *(short4_t*)&hvThi[col*LDHT + q*4]      = hh0;
            *(short4_t*)&hvTlo[col*LDHT + q*4]      = hl0;
            *(short4_t*)&hvThi[col*LDHT + 16 + q*4] = hh1;
            *(short4_t*)&hvTlo[col*LDHT + 16 + q*4] = hl1;
        }
        if (t < 512) {     // M bf16 hi/lo in A-layout
            #pragma unroll
            for (int idx = t; idx < 1024; idx += 512) {
                const int r = idx >> 5, j = idx & 31;
                const float g = gamma_tab[l*NVOC + atom_s[j]];
                const float v = expf(-g * d2s[r*LDM + j]);
                const short hb = f2bf(v);
                MAhi[r*LDMA + j] = hb;
                MAlo[r*LDMA + j] = f2bf(v - bf2f(hb));
            }
        }
        __syncthreads();   // B1: hvT + MA visible; GEMM reads of x done

        // P = M @ hv (C-layout, same lane mapping as hv registers)
        f32x4 p0 = (f32x4){0.f,0.f,0.f,0.f};
        f32x4 p1 = (f32x4){0.f,0.f,0.f,0.f};
        {
            const short8_t bh  = *(const short8_t*)&hvThi[col*LDHT + q*8];
            const short8_t bl  = *(const short8_t*)&hvTlo[col*LDHT + q*8];
            const short8_t a0h = *(const short8_t*)&MAhi[ml*LDMA + q*8];
            const short8_t a0l = *(const short8_t*)&MAlo[ml*LDMA + q*8];
            const short8_t a1h = *(const short8_t*)&MAhi[(16+ml)*LDMA + q*8];
            const short8_t a1l = *(const short8_t*)&MAlo[(16+ml)*LDMA + q*8];
            p0 = __builtin_amdgcn_mfma_f32_16x16x32_bf16(a0h, bh, p0, 0,0,0);
            p0 = __builtin_amdgcn_mfma_f32_16x16x32_bf16(a0h, bl, p0, 0,0,0);
            p0 = __builtin_amdgcn_mfma_f32_16x16x32_bf16(a0l, bh, p0, 0,0,0);
            p1 = __builtin_amdgcn_mfma_f32_16x16x32_bf16(a1h, bh, p1, 0,0,0);
            p1 = __builtin_amdgcn_mfma_f32_16x16x32_bf16(a1h, bl, p1, 0,0,0);
            p1 = __builtin_amdgcn_mfma_f32_16x16x32_bf16(a1l, bh, p1, 0,0,0);
        }
        // x = hv + P (registers), norm partials, bf16 split writes
        float xv0[4], xv1[4], r0[4], r1[4];
        #pragma unroll
        for (int i = 0; i < 4; ++i) {
            xv0[i] = hv0[i] + p0[i];
            xv1[i] = hv1[i] + p1[i];
            r0[i] = colok ? xv0[i]*xv0[i] : 0.f;
            r1[i] = colok ? xv1[i]*xv1[i] : 0.f;
        }
        #pragma unroll
        for (int m = 1; m < 16; m <<= 1) {
            #pragma unroll
            for (int i = 0; i < 4; ++i) {
                r0[i] += __shfl_xor(r0[i], m);
                r1[i] += __shfl_xor(r1[i], m);
            }
        }
        if (ml == 0) {
            float* sb = scaleSum[l & 1];
            #pragma unroll
            for (int i = 0; i < 4; ++i) {
                atomicAdd(&sb[q*4 + i],      r0[i]);
                atomicAdd(&sb[16 + q*4 + i], r1[i]);
            }
        }
        if (colok) {
            #pragma unroll
            for (int i = 0; i < 4; ++i) {
                const int ra = q*4 + i, rb = ra + 16;
                const short ha = f2bf(xv0[i]);
                xHi[ra*LDX + col] = ha;
                xLo[ra*LDX + col] = f2bf(xv0[i] - bf2f(ha));
                const short hb = f2bf(xv1[i]);
                xHi[rb*LDX + col] = hb;
                xLo[rb*LDX + col] = f2bf(xv1[i] - bf2f(hb));
            }
        }
        if (t < 32) scaleSum[(l+1) & 1][t] = 0.f;   // zero next buffer
        __syncthreads();   // B2: x splits + scaleSum visible
    }

    // ---- 3 out layers ----
    float* mv0 = d2s;         // reuse (d^2 no longer needed)
    float* mv1 = d2s + 256;
    for (int ol = 0; ol < 3; ++ol) {
        f32x4 macc[2];
        gemm_mfma(xHi, xLo, W2 + (size_t)(6+ol)*WL, w, lane, macc);
        float sc0[4], sc1[4];
        if (ol == 0) {
            const float* sb = scaleSum[1];   // layer 5 wrote buf[5&1]=1
            const float4 ss0 = *(const float4*)&sb[q*4];
            const float4 ss1 = *(const float4*)&sb[16 + q*4];
            sc0[0]=1.0f/fmaxf(sqrtf(ss0.x),1e-12f); sc0[1]=1.0f/fmaxf(sqrtf(ss0.y),1e-12f);
            sc0[2]=1.0f/fmaxf(sqrtf(ss0.z),1e-12f); sc0[3]=1.0f/fmaxf(sqrtf(ss0.w),1e-12f);
            sc1[0]=1.0f/fmaxf(sqrtf(ss1.x),1e-12f); sc1[1]=1.0f/fmaxf(sqrtf(ss1.y),1e-12f);
            sc1[2]=1.0f/fmaxf(sqrtf(ss1.z),1e-12f); sc1[3]=1.0f/fmaxf(sqrtf(ss1.w),1e-12f);
        } else {
            #pragma unroll
            for (int i = 0; i < 4; ++i) { sc0[i] = 1.f; sc1[i] = 1.f; }
        }
        const float bias = colok ? Wob[ol*DIMN + col] : 0.f;
        float av0[4], av1[4];
        #pragma unroll
        for (int i = 0; i < 4; ++i) {
            av0[i] = fmaxf(fmaf(macc[0][i], sc0[i], bias), 0.f);
            av1[i] = fmaxf(fmaf(macc[1][i], sc1[i], bias), 0.f);
        }
        __syncthreads();   // B1: all GEMM reads of x done
        if (ol < 2) {
            if (colok) {
                #pragma unroll
                for (int i = 0; i < 4; ++i) {
                    const int ra = q*4 + i, rb = ra + 16;
                    const short ha = f2bf(av0[i]);
                    xHi[ra*LDX + col] = ha;
                    xLo[ra*LDX + col] = f2bf(av0[i] - bf2f(ha));
                    const short hb = f2bf(av1[i]);
                    xHi[rb*LDX + col] = hb;
                    xLo[rb*LDX + col] = f2bf(av1[i] - bf2f(hb));
                }
            }
        } else {
            // molecule sum over rows: all 32 rows of `col` live in lanes {q*16+ml}
            float s = 0.f;
            if (colok) {
                #pragma unroll
                for (int i = 0; i < 4; ++i) s += av0[i] + av1[i];
            }
            s += __shfl_xor(s, 16);
            s += __shfl_xor(s, 32);
            if (q == 0 && colok) mv0[col] = s;
            if (t >= 200 && t < DPD) mv0[t] = adducts[mol*4 + (t - 200)];
        }
        __syncthreads();   // B2
    }

    // ---- 3 pred layers on [204] vector ----
    float* pc = mv0;
    float* pn = mv1;
    for (int l = 0; l < 3; ++l) {
        if (t < DPD) {
            float acc = Wpb[l*DPD + t];
            const float* Wl = Wpw + l*DPD*DPD;
            #pragma unroll 4
            for (int k = 0; k < DPD; ++k)
                acc = fmaf(pc[k], Wl[k*DPD + t], acc);
            pn[t] = fmaxf(acc, 0.f);
        }
        __syncthreads();
        float* tp = pc; pc = pn; pn = tp;
    }

    // ---- final property head ----
    float v = (t < DPD) ? pc[t] * Wprw[t] : 0.f;
    #pragma unroll
    for (int m = 1; m < 64; m <<= 1) v += __shfl_xor(v, m);
    if (lane == 0) red16[w] = v;
    __syncthreads();
    if (t == 0) {
        float s = Wprb[0];
        #pragma unroll
        for (int ww = 0; ww < 13; ++ww) s += red16[ww];
        out[mol] = s;
    }
}

extern "C" void kernel_launch(void* const* d_in, const int* in_sizes, int n_in,
                              void* d_out, int out_size, void* d_ws, size_t ws_size,
                              hipStream_t stream) {
    const int*   atoms   = (const int*)  d_in[0];
    const float* dist    = (const float*)d_in[1];
    const float* adducts = (const float*)d_in[2];
    const float* embed   = (const float*)d_in[3];
    const float* gamma_t = (const float*)d_in[4];
    const float* Waw     = (const float*)d_in[5];
    const float* Wab     = (const float*)d_in[6];
    const float* Wow     = (const float*)d_in[7];
    const float* Wob     = (const float*)d_in[8];
    const float* Wpw     = (const float*)d_in[9];
    const float* Wpb     = (const float*)d_in[10];
    const float* Wprw    = (const float*)d_in[11];
    const float* Wprb    = (const float*)d_in[12];
    (void)in_sizes; (void)n_in; (void)ws_size; (void)out_size;

    short* W2 = (short*)d_ws;   // 9*WL shorts = ~1.68 MB

    conv_kernel<<<dim3(512), dim3(256), 0, stream>>>(Waw, Wow, W2);
    mgnn_kernel<<<dim3(256), dim3(832), 0, stream>>>(
        atoms, dist, adducts, embed, gamma_t,
        Waw, Wab, Wow, Wob, Wpw, Wpb, Wprw, Wprb,
        W2, (float*)d_out);
}

// Round 14
// 406.177 us; speedup vs baseline: 1.0996x; 1.0996x over previous
//
#include <hip/hip_runtime.h>
#include <hip/hip_bf16.h>
#include <cmath>

// Problem constants
#define NVOC 100
#define DIMN 200
#define LDX  232      // xHi/xLo stride (bf16 elems)
#define LDHT 40       // hvT stride (bf16): hvT[c][j], j=0..31
#define LDMA 40       // MA stride (bf16): MA[r][j]
#define DPD  204
#define LDM  36
#define NTOT 8192
#define KP   224      // K padded to 7*32
#define NP   208      // N padded to 13*16
#define WHALF (NP*KP)
#define WL    (2*WHALF)
// grid = 256 (1 block/CU), block = 832 = 13 waves. Whole layer pipeline in MFMA
// C-layout registers (row=q*4+i, col=16w+ml). 2 barriers/layer. Pred layers
// parallelized over all 13 waves (4 k-slices x 204 cols + LDS reduce).

typedef __attribute__((ext_vector_type(8))) short short8_t;
typedef __attribute__((ext_vector_type(4))) short short4_t;
typedef __attribute__((ext_vector_type(4))) float f32x4;

__device__ __forceinline__ short f2bf(float v) {
    __hip_bfloat16 h = __float2bfloat16(v);
    return *reinterpret_cast<short*>(&h);
}
__device__ __forceinline__ float bf2f(short s) {
    __hip_bfloat16 h = *reinterpret_cast<__hip_bfloat16*>(&s);
    return __bfloat162float(h);
}

// ---- W conversion pre-pass: fp32 [k][n] -> bf16 hi/lo [n][k], padded ----
__global__ void conv_kernel(const float* __restrict__ Waw,
                            const float* __restrict__ Wow,
                            short* __restrict__ W2)
{
    const int total = 9 * NP * KP;
    for (int idx = blockIdx.x * 256 + threadIdx.x; idx < total;
         idx += gridDim.x * 256) {
        const int l = idx / (NP*KP);
        const int rem = idx % (NP*KP);
        const int n = rem / KP;
        const int k = rem % KP;
        float v = 0.f;
        if (n < DIMN && k < DIMN)
            v = (l < 6) ? Waw[l*40000 + k*DIMN + n]
                        : Wow[(l-6)*40000 + k*DIMN + n];
        const short hi = f2bf(v);
        const short lo = f2bf(v - bf2f(hi));
        W2[(size_t)l*WL + n*KP + k]         = hi;
        W2[(size_t)l*WL + WHALF + n*KP + k] = lo;
    }
}

// MFMA GEMM: wave w computes cols 16w..16w+15, both 16-row M-tiles, full K.
__device__ __forceinline__ void gemm_mfma(const short* __restrict__ xHi,
                                          const short* __restrict__ xLo,
                                          const short* __restrict__ Wl,
                                          int w, int lane, f32x4 acc[2])
{
    acc[0] = (f32x4){0.f,0.f,0.f,0.f};
    acc[1] = (f32x4){0.f,0.f,0.f,0.f};
    const int m = lane & 15;
    const int q = lane >> 4;
    const short* aH0 = xHi + m*LDX + q*8;
    const short* aL0 = xLo + m*LDX + q*8;
    const short* aH1 = aH0 + 16*LDX;
    const short* aL1 = aL0 + 16*LDX;
    const short* bH  = Wl + (w*16 + m)*KP + q*8;
    const short* bL  = bH + WHALF;
    #pragma unroll
    for (int ks = 0; ks < 7; ++ks) {
        const int ko = ks * 32;
        const short8_t ah0 = *(const short8_t*)(aH0 + ko);
        const short8_t al0 = *(const short8_t*)(aL0 + ko);
        const short8_t ah1 = *(const short8_t*)(aH1 + ko);
        const short8_t al1 = *(const short8_t*)(aL1 + ko);
        const short8_t bh  = *(const short8_t*)(bH + ko);
        const short8_t bl  = *(const short8_t*)(bL + ko);
        acc[0] = __builtin_amdgcn_mfma_f32_16x16x32_bf16(ah0, bh, acc[0], 0,0,0);
        acc[0] = __builtin_amdgcn_mfma_f32_16x16x32_bf16(ah0, bl, acc[0], 0,0,0);
        acc[0] = __builtin_amdgcn_mfma_f32_16x16x32_bf16(al0, bh, acc[0], 0,0,0);
        acc[1] = __builtin_amdgcn_mfma_f32_16x16x32_bf16(ah1, bh, acc[1], 0,0,0);
        acc[1] = __builtin_amdgcn_mfma_f32_16x16x32_bf16(ah1, bl, acc[1], 0,0,0);
        acc[1] = __builtin_amdgcn_mfma_f32_16x16x32_bf16(al1, bh, acc[1], 0,0,0);
    }
}

__global__ __launch_bounds__(832)
void mgnn_kernel(const int*   __restrict__ atoms,
                 const float* __restrict__ dist,
                 const float* __restrict__ adducts,
                 const float* __restrict__ embed,
                 const float* __restrict__ gamma_tab,
                 const float* __restrict__ Waw,
                 const float* __restrict__ Wab,
                 const float* __restrict__ Wow,
                 const float* __restrict__ Wob,
                 const float* __restrict__ Wpw,
                 const float* __restrict__ Wpb,
                 const float* __restrict__ Wprw,
                 const float* __restrict__ Wprb,
                 const short* __restrict__ W2,
                 float* __restrict__ out)
{
    __shared__ short xHi[32*LDX];      // x high bf16
    __shared__ short xLo[32*LDX];      // x low  bf16
    __shared__ short hvThi[NP*LDHT];   // hv^T high (B-layout for P)
    __shared__ short hvTlo[NP*LDHT];
    __shared__ short MAhi[32*LDMA];    // M high (A-layout)
    __shared__ short MAlo[32*LDMA];
    __shared__ float d2s[32*LDM];      // d^2; later reused as mv buffers
    __shared__ float ppart[4*204];     // pred-layer partials
    __shared__ float scaleSum[2][32];  // double-buffered row sum-of-squares
    __shared__ float red16[16];
    __shared__ int   atom_s[32];
    // total ~78 KB

    const int mol  = blockIdx.x;
    const int t    = threadIdx.x;
    const int base = mol * 32;
    const int w    = t >> 6;          // wave 0..12 = ntile
    const int lane = t & 63;
    const int ml   = lane & 15;
    const int q    = lane >> 4;
    const int col  = 16*w + ml;       // this lane's output column (C-layout)
    const bool colok = (col < DIMN);

    // ---- init ----
    if (t < 32) atom_s[t] = atoms[base + t];
    if (t < 32)            scaleSum[0][t] = 0.f;
    else if (t < 64)       scaleSum[1][t-32] = 0.f;
    if (t < 512) {
        const int j  = t >> 4;
        const int c2 = (t & 15) * 2;
        const float2 dd = *(const float2*)&dist[(size_t)(base + j) * NTOT + base + c2];
        d2s[j*LDM + c2]     = dd.x * dd.x;
        d2s[j*LDM + c2 + 1] = dd.y * dd.y;
    }
    for (int idx = t; idx < 32*DIMN; idx += 832) {   // x0 = embed[atoms], split
        const int r = idx / DIMN, c = idx % DIMN;
        const float v = embed[atoms[base + r]*DIMN + c];
        const short hi = f2bf(v);
        xHi[r*LDX + c] = hi;
        xLo[r*LDX + c] = f2bf(v - bf2f(hi));
    }
    for (int idx = t; idx < 32*32; idx += 832) {     // zero k-pad 200..231
        const int r = idx >> 5, c = DIMN + (idx & 31);
        xHi[r*LDX + c] = 0;
        xLo[r*LDX + c] = 0;
    }
    __syncthreads();

    // ---- 6 hidden layers (2 barriers each) ----
    for (int l = 0; l < 6; ++l) {
        f32x4 macc[2];
        gemm_mfma(xHi, xLo, W2 + (size_t)l*WL, w, lane, macc);

        // combine in C-layout registers: hv = relu(sum * s_prev + b)
        float sc0[4], sc1[4];
        if (l == 0) {
            #pragma unroll
            for (int i = 0; i < 4; ++i) { sc0[i] = 1.f; sc1[i] = 1.f; }
        } else {
            const float* sb = scaleSum[(l-1)&1];
            const float4 ss0 = *(const float4*)&sb[q*4];
            const float4 ss1 = *(const float4*)&sb[16 + q*4];
            sc0[0]=1.0f/fmaxf(sqrtf(ss0.x),1e-12f); sc0[1]=1.0f/fmaxf(sqrtf(ss0.y),1e-12f);
            sc0[2]=1.0f/fmaxf(sqrtf(ss0.z),1e-12f); sc0[3]=1.0f/fmaxf(sqrtf(ss0.w),1e-12f);
            sc1[0]=1.0f/fmaxf(sqrtf(ss1.x),1e-12f); sc1[1]=1.0f/fmaxf(sqrtf(ss1.y),1e-12f);
            sc1[2]=1.0f/fmaxf(sqrtf(ss1.z),1e-12f); sc1[3]=1.0f/fmaxf(sqrtf(ss1.w),1e-12f);
        }
        const float bias = colok ? Wab[l*DIMN + col] : 0.f;
        float hv0[4], hv1[4];
        #pragma unroll
        for (int i = 0; i < 4; ++i) {
            hv0[i] = fmaxf(fmaf(macc[0][i], sc0[i], bias), 0.f);
            hv1[i] = fmaxf(fmaf(macc[1][i], sc1[i], bias), 0.f);
        }
        // hvT[col][j] bf16 hi/lo (B-operand layout for P); rows>=200 are 0
        {
            short4_t hh0, hl0, hh1, hl1;
            #pragma unroll
            for (int i = 0; i < 4; ++i) {
                const short a = f2bf(hv0[i]); hh0[i] = a; hl0[i] = f2bf(hv0[i] - bf2f(a));
                const short b = f2bf(hv1[i]); hh1[i] = b; hl1[i] = f2bf(hv1[i] - bf2f(b));
            }
            *(short4_t*)&hvThi[col*LDHT + q*4]      = hh0;
            *(short4_t*)&hvTlo[col*LDHT + q*4]      = hl0;
            *(short4_t*)&hvThi[col*LDHT + 16 + q*4] = hh1;
            *(short4_t*)&hvTlo[col*LDHT + 16 + q*4] = hl1;
        }
        if (t < 512) {     // M bf16 hi/lo in A-layout
            #pragma unroll
            for (int idx = t; idx < 1024; idx += 512) {
                const int r = idx >> 5, j = idx & 31;
                const float g = gamma_tab[l*NVOC + atom_s[j]];
                const float v = expf(-g * d2s[r*LDM + j]);
                const short hb = f2bf(v);
                MAhi[r*LDMA + j] = hb;
                MAlo[r*LDMA + j] = f2bf(v - bf2f(hb));
            }
        }
        __syncthreads();   // B1: hvT + MA visible; GEMM reads of x done

        // P = M @ hv (C-layout, same lane mapping as hv registers)
        f32x4 p0 = (f32x4){0.f,0.f,0.f,0.f};
        f32x4 p1 = (f32x4){0.f,0.f,0.f,0.f};
        {
            const short8_t bh  = *(const short8_t*)&hvThi[col*LDHT + q*8];
            const short8_t bl  = *(const short8_t*)&hvTlo[col*LDHT + q*8];
            const short8_t a0h = *(const short8_t*)&MAhi[ml*LDMA + q*8];
            const short8_t a0l = *(const short8_t*)&MAlo[ml*LDMA + q*8];
            const short8_t a1h = *(const short8_t*)&MAhi[(16+ml)*LDMA + q*8];
            const short8_t a1l = *(const short8_t*)&MAlo[(16+ml)*LDMA + q*8];
            p0 = __builtin_amdgcn_mfma_f32_16x16x32_bf16(a0h, bh, p0, 0,0,0);
            p0 = __builtin_amdgcn_mfma_f32_16x16x32_bf16(a0h, bl, p0, 0,0,0);
            p0 = __builtin_amdgcn_mfma_f32_16x16x32_bf16(a0l, bh, p0, 0,0,0);
            p1 = __builtin_amdgcn_mfma_f32_16x16x32_bf16(a1h, bh, p1, 0,0,0);
            p1 = __builtin_amdgcn_mfma_f32_16x16x32_bf16(a1h, bl, p1, 0,0,0);
            p1 = __builtin_amdgcn_mfma_f32_16x16x32_bf16(a1l, bh, p1, 0,0,0);
        }
        // x = hv + P (registers), norm partials, bf16 split writes
        float xv0[4], xv1[4], r0[4], r1[4];
        #pragma unroll
        for (int i = 0; i < 4; ++i) {
            xv0[i] = hv0[i] + p0[i];
            xv1[i] = hv1[i] + p1[i];
            r0[i] = colok ? xv0[i]*xv0[i] : 0.f;
            r1[i] = colok ? xv1[i]*xv1[i] : 0.f;
        }
        #pragma unroll
        for (int m = 1; m < 16; m <<= 1) {
            #pragma unroll
            for (int i = 0; i < 4; ++i) {
                r0[i] += __shfl_xor(r0[i], m);
                r1[i] += __shfl_xor(r1[i], m);
            }
        }
        if (ml == 0) {
            float* sb = scaleSum[l & 1];
            #pragma unroll
            for (int i = 0; i < 4; ++i) {
                atomicAdd(&sb[q*4 + i],      r0[i]);
                atomicAdd(&sb[16 + q*4 + i], r1[i]);
            }
        }
        if (colok) {
            #pragma unroll
            for (int i = 0; i < 4; ++i) {
                const int ra = q*4 + i, rb = ra + 16;
                const short ha = f2bf(xv0[i]);
                xHi[ra*LDX + col] = ha;
                xLo[ra*LDX + col] = f2bf(xv0[i] - bf2f(ha));
                const short hb = f2bf(xv1[i]);
                xHi[rb*LDX + col] = hb;
                xLo[rb*LDX + col] = f2bf(xv1[i] - bf2f(hb));
            }
        }
        if (t < 32) scaleSum[(l+1) & 1][t] = 0.f;   // zero next buffer
        __syncthreads();   // B2: x splits + scaleSum visible
    }

    // ---- 3 out layers ----
    float* mv0 = d2s;         // reuse (d^2 no longer needed)
    float* mv1 = d2s + 256;
    for (int ol = 0; ol < 3; ++ol) {
        f32x4 macc[2];
        gemm_mfma(xHi, xLo, W2 + (size_t)(6+ol)*WL, w, lane, macc);
        float sc0[4], sc1[4];
        if (ol == 0) {
            const float* sb = scaleSum[1];   // layer 5 wrote buf 1
            const float4 ss0 = *(const float4*)&sb[q*4];
            const float4 ss1 = *(const float4*)&sb[16 + q*4];
            sc0[0]=1.0f/fmaxf(sqrtf(ss0.x),1e-12f); sc0[1]=1.0f/fmaxf(sqrtf(ss0.y),1e-12f);
            sc0[2]=1.0f/fmaxf(sqrtf(ss0.z),1e-12f); sc0[3]=1.0f/fmaxf(sqrtf(ss0.w),1e-12f);
            sc1[0]=1.0f/fmaxf(sqrtf(ss1.x),1e-12f); sc1[1]=1.0f/fmaxf(sqrtf(ss1.y),1e-12f);
            sc1[2]=1.0f/fmaxf(sqrtf(ss1.z),1e-12f); sc1[3]=1.0f/fmaxf(sqrtf(ss1.w),1e-12f);
        } else {
            #pragma unroll
            for (int i = 0; i < 4; ++i) { sc0[i] = 1.f; sc1[i] = 1.f; }
        }
        const float bias = colok ? Wob[ol*DIMN + col] : 0.f;
        float av0[4], av1[4];
        #pragma unroll
        for (int i = 0; i < 4; ++i) {
            av0[i] = fmaxf(fmaf(macc[0][i], sc0[i], bias), 0.f);
            av1[i] = fmaxf(fmaf(macc[1][i], sc1[i], bias), 0.f);
        }
        __syncthreads();   // B1: all GEMM reads of x done
        if (ol < 2) {
            if (colok) {
                #pragma unroll
                for (int i = 0; i < 4; ++i) {
                    const int ra = q*4 + i, rb = ra + 16;
                    const short ha = f2bf(av0[i]);
                    xHi[ra*LDX + col] = ha;
                    xLo[ra*LDX + col] = f2bf(av0[i] - bf2f(ha));
                    const short hb = f2bf(av1[i]);
                    xHi[rb*LDX + col] = hb;
                    xLo[rb*LDX + col] = f2bf(av1[i] - bf2f(hb));
                }
            }
        } else {
            // molecule sum: all 32 rows of `col` live in lanes {q*16+ml} of wave w
            float s = 0.f;
            if (colok) {
                #pragma unroll
                for (int i = 0; i < 4; ++i) s += av0[i] + av1[i];
            }
            s += __shfl_xor(s, 16);
            s += __shfl_xor(s, 32);
            if (q == 0 && colok) mv0[col] = s;
            if (t >= 200 && t < DPD) mv0[t] = adducts[mol*4 + (t - 200)];
        }
        __syncthreads();   // B2
    }

    // ---- 3 pred layers on [204] vector, parallelized over all 13 waves ----
    float* pc = mv0;
    float* pn = mv1;
    for (int l = 0; l < 3; ++l) {
        if (t < 816) {
            const int ks = t / 204;          // k-slice 0..3 (51 k's each)
            const int pcol = t - ks * 204;   // output column
            const float* Wl = Wpw + l*DPD*DPD;
            const int k0 = ks * 51;
            float p = 0.f;
            #pragma unroll 3
            for (int k = k0; k < k0 + 51; ++k)
                p = fmaf(pc[k], Wl[k*DPD + pcol], p);   // pc broadcast, Wl coalesced
            ppart[ks*204 + pcol] = p;
        }
        __syncthreads();
        if (t < DPD) {
            const float v = Wpb[l*DPD + t] + ppart[t] + ppart[204 + t]
                          + ppart[408 + t] + ppart[612 + t];
            pn[t] = fmaxf(v, 0.f);
        }
        __syncthreads();
        float* tp = pc; pc = pn; pn = tp;
    }

    // ---- final property head ----
    float v = (t < DPD) ? pc[t] * Wprw[t] : 0.f;
    #pragma unroll
    for (int m = 1; m < 64; m <<= 1) v += __shfl_xor(v, m);
    if (lane == 0) red16[w] = v;
    __syncthreads();
    if (t == 0) {
        float s = Wprb[0];
        #pragma unroll
        for (int ww = 0; ww < 13; ++ww) s += red16[ww];
        out[mol] = s;
    }
}

extern "C" void kernel_launch(void* const* d_in, const int* in_sizes, int n_in,
                              void* d_out, int out_size, void* d_ws, size_t ws_size,
                              hipStream_t stream) {
    const int*   atoms   = (const int*)  d_in[0];
    const float* dist    = (const float*)d_in[1];
    const float* adducts = (const float*)d_in[2];
    const float* embed   = (const float*)d_in[3];
    const float* gamma_t = (const float*)d_in[4];
    const float* Waw     = (const float*)d_in[5];
    const float* Wab     = (const float*)d_in[6];
    const float* Wow     = (const float*)d_in[7];
    const float* Wob     = (const float*)d_in[8];
    const float* Wpw     = (const float*)d_in[9];
    const float* Wpb     = (const float*)d_in[10];
    const float* Wprw    = (const float*)d_in[11];
    const float* Wprb    = (const float*)d_in[12];
    (void)in_sizes; (void)n_in; (void)ws_size; (void)out_size;

    short* W2 = (short*)d_ws;   // 9*WL shorts = ~1.68 MB

    conv_kernel<<<dim3(512), dim3(256), 0, stream>>>(Waw, Wow, W2);
    mgnn_kernel<<<dim3(256), dim3(832), 0, stream>>>(
        atoms, dist, adducts, embed, gamma_t,
        Waw, Wab, Wow, Wob, Wpw, Wpb, Wprw, Wprb,
        W2, (float*)d_out);
}

// Round 15
// 400.204 us; speedup vs baseline: 1.1160x; 1.0149x over previous
//
#include <hip/hip_runtime.h>
#include <hip/hip_bf16.h>
#include <cmath>

// Problem constants
#define NVOC 100
#define DIMN 200
#define LDX  232      // xHi/xLo stride (bf16 elems)
#define LDHT 40       // hvT stride (bf16): hvT[c][j], j=0..31
#define LDMA 40       // MA stride (bf16): MA[l][r][j]
#define DPD  204
#define LDM  36
#define NTOT 8192
#define KP   224      // K padded to 7*32
#define NP   208      // N padded to 13*16
#define WHALF (NP*KP)
#define WL    (2*WHALF)
// grid = 256 (1 block/CU), block = 832 = 13 waves. MFMA C-layout register
// pipeline (row=q*4+i, col=16w+ml), 2 barriers/layer. R15: all 6 layers' M
// (bf16 hi/lo) precomputed in init (off the critical path); W2 hi-B-frags
// register-prefetched one layer ahead (issued after B1, consumed after B2).

typedef __attribute__((ext_vector_type(8))) short short8_t;
typedef __attribute__((ext_vector_type(4))) short short4_t;
typedef __attribute__((ext_vector_type(4))) float f32x4;

__device__ __forceinline__ short f2bf(float v) {
    __hip_bfloat16 h = __float2bfloat16(v);
    return *reinterpret_cast<short*>(&h);
}
__device__ __forceinline__ float bf2f(short s) {
    __hip_bfloat16 h = *reinterpret_cast<__hip_bfloat16*>(&s);
    return __bfloat162float(h);
}

// ---- W conversion pre-pass: fp32 [k][n] -> bf16 hi/lo [n][k], padded ----
__global__ void conv_kernel(const float* __restrict__ Waw,
                            const float* __restrict__ Wow,
                            short* __restrict__ W2)
{
    const int total = 9 * NP * KP;
    for (int idx = blockIdx.x * 256 + threadIdx.x; idx < total;
         idx += gridDim.x * 256) {
        const int l = idx / (NP*KP);
        const int rem = idx % (NP*KP);
        const int n = rem / KP;
        const int k = rem % KP;
        float v = 0.f;
        if (n < DIMN && k < DIMN)
            v = (l < 6) ? Waw[l*40000 + k*DIMN + n]
                        : Wow[(l-6)*40000 + k*DIMN + n];
        const short hi = f2bf(v);
        const short lo = f2bf(v - bf2f(hi));
        W2[(size_t)l*WL + n*KP + k]         = hi;
        W2[(size_t)l*WL + WHALF + n*KP + k] = lo;
    }
}

// Prefetch the 7 hi B-frags of a layer into registers (28 VGPRs).
__device__ __forceinline__ void prefB(const short* __restrict__ Wl,
                                      int w, int lane, short8_t bhPre[7])
{
    const short* bH = Wl + (w*16 + (lane & 15))*KP + (lane >> 4)*8;
    #pragma unroll
    for (int ks = 0; ks < 7; ++ks)
        bhPre[ks] = *(const short8_t*)(bH + ks*32);
}

// MFMA GEMM consuming prefetched hi B-frags; lo B-frags loaded in-loop.
__device__ __forceinline__ void gemm_mfma_pre(const short* __restrict__ xHi,
                                              const short* __restrict__ xLo,
                                              const short* __restrict__ Wl,
                                              const short8_t bhPre[7],
                                              int w, int lane, f32x4 acc[2])
{
    acc[0] = (f32x4){0.f,0.f,0.f,0.f};
    acc[1] = (f32x4){0.f,0.f,0.f,0.f};
    const int m = lane & 15;
    const int q = lane >> 4;
    const short* aH0 = xHi + m*LDX + q*8;
    const short* aL0 = xLo + m*LDX + q*8;
    const short* aH1 = aH0 + 16*LDX;
    const short* aL1 = aL0 + 16*LDX;
    const short* bL  = Wl + WHALF + (w*16 + m)*KP + q*8;
    #pragma unroll
    for (int ks = 0; ks < 7; ++ks) {
        const int ko = ks * 32;
        const short8_t ah0 = *(const short8_t*)(aH0 + ko);
        const short8_t al0 = *(const short8_t*)(aL0 + ko);
        const short8_t ah1 = *(const short8_t*)(aH1 + ko);
        const short8_t al1 = *(const short8_t*)(aL1 + ko);
        const short8_t bh  = bhPre[ks];
        const short8_t bl  = *(const short8_t*)(bL + ko);
        acc[0] = __builtin_amdgcn_mfma_f32_16x16x32_bf16(ah0, bh, acc[0], 0,0,0);
        acc[0] = __builtin_amdgcn_mfma_f32_16x16x32_bf16(ah0, bl, acc[0], 0,0,0);
        acc[0] = __builtin_amdgcn_mfma_f32_16x16x32_bf16(al0, bh, acc[0], 0,0,0);
        acc[1] = __builtin_amdgcn_mfma_f32_16x16x32_bf16(ah1, bh, acc[1], 0,0,0);
        acc[1] = __builtin_amdgcn_mfma_f32_16x16x32_bf16(ah1, bl, acc[1], 0,0,0);
        acc[1] = __builtin_amdgcn_mfma_f32_16x16x32_bf16(al1, bh, acc[1], 0,0,0);
    }
}

__global__ __launch_bounds__(832)
void mgnn_kernel(const int*   __restrict__ atoms,
                 const float* __restrict__ dist,
                 const float* __restrict__ adducts,
                 const float* __restrict__ embed,
                 const float* __restrict__ gamma_tab,
                 const float* __restrict__ Waw,
                 const float* __restrict__ Wab,
                 const float* __restrict__ Wow,
                 const float* __restrict__ Wob,
                 const float* __restrict__ Wpw,
                 const float* __restrict__ Wpb,
                 const float* __restrict__ Wprw,
                 const float* __restrict__ Wprb,
                 const short* __restrict__ W2,
                 float* __restrict__ out)
{
    __shared__ short xHi[32*LDX];        // x high bf16
    __shared__ short xLo[32*LDX];        // x low  bf16
    __shared__ short hvThi[NP*LDHT];     // hv^T high (B-layout for P)
    __shared__ short hvTlo[NP*LDHT];
    __shared__ short MAhi[6*32*LDMA];    // all 6 layers' M high (A-layout)
    __shared__ short MAlo[6*32*LDMA];    // all 6 layers' M low
    __shared__ float d2s[32*LDM];        // d^2; later reused as mv buffers
    __shared__ float ppart[4*204];       // pred-layer partials
    __shared__ float scaleSum[2][32];    // double-buffered row sum-of-squares
    __shared__ float red16[16];
    __shared__ int   atom_s[32];
    // total ~102 KB < 160 KB

    const int mol  = blockIdx.x;
    const int t    = threadIdx.x;
    const int base = mol * 32;
    const int w    = t >> 6;          // wave 0..12 = ntile
    const int lane = t & 63;
    const int ml   = lane & 15;
    const int q    = lane >> 4;
    const int col  = 16*w + ml;       // this lane's output column (C-layout)
    const bool colok = (col < DIMN);

    short8_t bhPre[7];
    prefB(W2, w, lane, bhPre);        // layer-0 hi B-frags (in flight over init)

    // ---- init phase 1: atoms, d2s, x0 splits, pads ----
    if (t < 32) atom_s[t] = atoms[base + t];
    if (t < 32)            scaleSum[0][t] = 0.f;
    else if (t < 64)       scaleSum[1][t-32] = 0.f;
    if (t < 512) {
        const int j  = t >> 4;
        const int c2 = (t & 15) * 2;
        const float2 dd = *(const float2*)&dist[(size_t)(base + j) * NTOT + base + c2];
        d2s[j*LDM + c2]     = dd.x * dd.x;
        d2s[j*LDM + c2 + 1] = dd.y * dd.y;
    }
    for (int idx = t; idx < 32*DIMN; idx += 832) {   // x0 = embed[atoms], split
        const int r = idx / DIMN, c = idx % DIMN;
        const float v = embed[atoms[base + r]*DIMN + c];
        const short hi = f2bf(v);
        xHi[r*LDX + c] = hi;
        xLo[r*LDX + c] = f2bf(v - bf2f(hi));
    }
    for (int idx = t; idx < 32*32; idx += 832) {     // zero k-pad 200..231
        const int r = idx >> 5, c = DIMN + (idx & 31);
        xHi[r*LDX + c] = 0;
        xLo[r*LDX + c] = 0;
    }
    __syncthreads();   // d2s + atom_s visible

    // ---- init phase 2: precompute all 6 layers' M (bf16 hi/lo, A-layout) ----
    for (int idx = t; idx < 6*1024; idx += 832) {
        const int l = idx >> 10;
        const int rem = idx & 1023;
        const int r = rem >> 5, j = rem & 31;
        const float g = gamma_tab[l*NVOC + atom_s[j]];
        const float v = expf(-g * d2s[r*LDM + j]);
        const short hb = f2bf(v);
        MAhi[(l*32 + r)*LDMA + j] = hb;
        MAlo[(l*32 + r)*LDMA + j] = f2bf(v - bf2f(hb));
    }
    __syncthreads();

    // ---- 6 hidden layers (2 barriers each) ----
    for (int l = 0; l < 6; ++l) {
        f32x4 macc[2];
        gemm_mfma_pre(xHi, xLo, W2 + (size_t)l*WL, bhPre, w, lane, macc);

        // combine in C-layout registers: hv = relu(sum * s_prev + b)
        float sc0[4], sc1[4];
        if (l == 0) {
            #pragma unroll
            for (int i = 0; i < 4; ++i) { sc0[i] = 1.f; sc1[i] = 1.f; }
        } else {
            const float* sb = scaleSum[(l-1)&1];
            const float4 ss0 = *(const float4*)&sb[q*4];
            const float4 ss1 = *(const float4*)&sb[16 + q*4];
            sc0[0]=1.0f/fmaxf(sqrtf(ss0.x),1e-12f); sc0[1]=1.0f/fmaxf(sqrtf(ss0.y),1e-12f);
            sc0[2]=1.0f/fmaxf(sqrtf(ss0.z),1e-12f); sc0[3]=1.0f/fmaxf(sqrtf(ss0.w),1e-12f);
            sc1[0]=1.0f/fmaxf(sqrtf(ss1.x),1e-12f); sc1[1]=1.0f/fmaxf(sqrtf(ss1.y),1e-12f);
            sc1[2]=1.0f/fmaxf(sqrtf(ss1.z),1e-12f); sc1[3]=1.0f/fmaxf(sqrtf(ss1.w),1e-12f);
        }
        const float bias = colok ? Wab[l*DIMN + col] : 0.f;
        float hv0[4], hv1[4];
        #pragma unroll
        for (int i = 0; i < 4; ++i) {
            hv0[i] = fmaxf(fmaf(macc[0][i], sc0[i], bias), 0.f);
            hv1[i] = fmaxf(fmaf(macc[1][i], sc1[i], bias), 0.f);
        }
        // hvT[col][j] bf16 hi/lo (B-operand layout for P); rows>=200 are 0
        {
            short4_t hh0, hl0, hh1, hl1;
            #pragma unroll
            for (int i = 0; i < 4; ++i) {
                const short a = f2bf(hv0[i]); hh0[i] = a; hl0[i] = f2bf(hv0[i] - bf2f(a));
                const short b = f2bf(hv1[i]); hh1[i] = b; hl1[i] = f2bf(hv1[i] - bf2f(b));
            }
            *(short4_t*)&hvThi[col*LDHT + q*4]      = hh0;
            *(short4_t*)&hvTlo[col*LDHT + q*4]      = hl0;
            *(short4_t*)&hvThi[col*LDHT + 16 + q*4] = hh1;
            *(short4_t*)&hvTlo[col*LDHT + 16 + q*4] = hl1;
        }
        __syncthreads();   // B1: hvT visible; GEMM reads of x done

        // prefetch next layer's hi B-frags (in flight across P + B2)
        prefB(W2 + (size_t)(l+1)*WL, w, lane, bhPre);

        // P = M @ hv (C-layout, same lane mapping as hv registers)
        f32x4 p0 = (f32x4){0.f,0.f,0.f,0.f};
        f32x4 p1 = (f32x4){0.f,0.f,0.f,0.f};
        {
            const short* MAh = MAhi + l*32*LDMA;
            const short* MAl = MAlo + l*32*LDMA;
            const short8_t bh  = *(const short8_t*)&hvThi[col*LDHT + q*8];
            const short8_t bl  = *(const short8_t*)&hvTlo[col*LDHT + q*8];
            const short8_t a0h = *(const short8_t*)&MAh[ml*LDMA + q*8];
            const short8_t a0l = *(const short8_t*)&MAl[ml*LDMA + q*8];
            const short8_t a1h = *(const short8_t*)&MAh[(16+ml)*LDMA + q*8];
            const short8_t a1l = *(const short8_t*)&MAl[(16+ml)*LDMA + q*8];
            p0 = __builtin_amdgcn_mfma_f32_16x16x32_bf16(a0h, bh, p0, 0,0,0);
            p0 = __builtin_amdgcn_mfma_f32_16x16x32_bf16(a0h, bl, p0, 0,0,0);
            p0 = __builtin_amdgcn_mfma_f32_16x16x32_bf16(a0l, bh, p0, 0,0,0);
            p1 = __builtin_amdgcn_mfma_f32_16x16x32_bf16(a1h, bh, p1, 0,0,0);
            p1 = __builtin_amdgcn_mfma_f32_16x16x32_bf16(a1h, bl, p1, 0,0,0);
            p1 = __builtin_amdgcn_mfma_f32_16x16x32_bf16(a1l, bh, p1, 0,0,0);
        }
        // x = hv + P (registers), norm partials, bf16 split writes
        float xv0[4], xv1[4], r0[4], r1[4];
        #pragma unroll
        for (int i = 0; i < 4; ++i) {
            xv0[i] = hv0[i] + p0[i];
            xv1[i] = hv1[i] + p1[i];
            r0[i] = colok ? xv0[i]*xv0[i] : 0.f;
            r1[i] = colok ? xv1[i]*xv1[i] : 0.f;
        }
        #pragma unroll
        for (int m = 1; m < 16; m <<= 1) {
            #pragma unroll
            for (int i = 0; i < 4; ++i) {
                r0[i] += __shfl_xor(r0[i], m);
                r1[i] += __shfl_xor(r1[i], m);
            }
        }
        if (ml == 0) {
            float* sb = scaleSum[l & 1];
            #pragma unroll
            for (int i = 0; i < 4; ++i) {
                atomicAdd(&sb[q*4 + i],      r0[i]);
                atomicAdd(&sb[16 + q*4 + i], r1[i]);
            }
        }
        if (colok) {
            #pragma unroll
            for (int i = 0; i < 4; ++i) {
                const int ra = q*4 + i, rb = ra + 16;
                const short ha = f2bf(xv0[i]);
                xHi[ra*LDX + col] = ha;
                xLo[ra*LDX + col] = f2bf(xv0[i] - bf2f(ha));
                const short hb = f2bf(xv1[i]);
                xHi[rb*LDX + col] = hb;
                xLo[rb*LDX + col] = f2bf(xv1[i] - bf2f(hb));
            }
        }
        if (t < 32) scaleSum[(l+1) & 1][t] = 0.f;   // zero next buffer
        __syncthreads();   // B2: x splits + scaleSum visible
    }

    // ---- 3 out layers ----
    float* mv0 = d2s;         // reuse (d^2 no longer needed)
    float* mv1 = d2s + 256;
    for (int ol = 0; ol < 3; ++ol) {
        f32x4 macc[2];
        gemm_mfma_pre(xHi, xLo, W2 + (size_t)(6+ol)*WL, bhPre, w, lane, macc);
        if (ol < 2) prefB(W2 + (size_t)(7+ol)*WL, w, lane, bhPre);
        float sc0[4], sc1[4];
        if (ol == 0) {
            const float* sb = scaleSum[1];   // layer 5 wrote buf 1
            const float4 ss0 = *(const float4*)&sb[q*4];
            const float4 ss1 = *(const float4*)&sb[16 + q*4];
            sc0[0]=1.0f/fmaxf(sqrtf(ss0.x),1e-12f); sc0[1]=1.0f/fmaxf(sqrtf(ss0.y),1e-12f);
            sc0[2]=1.0f/fmaxf(sqrtf(ss0.z),1e-12f); sc0[3]=1.0f/fmaxf(sqrtf(ss0.w),1e-12f);
            sc1[0]=1.0f/fmaxf(sqrtf(ss1.x),1e-12f); sc1[1]=1.0f/fmaxf(sqrtf(ss1.y),1e-12f);
            sc1[2]=1.0f/fmaxf(sqrtf(ss1.z),1e-12f); sc1[3]=1.0f/fmaxf(sqrtf(ss1.w),1e-12f);
        } else {
            #pragma unroll
            for (int i = 0; i < 4; ++i) { sc0[i] = 1.f; sc1[i] = 1.f; }
        }
        const float bias = colok ? Wob[ol*DIMN + col] : 0.f;
        float av0[4], av1[4];
        #pragma unroll
        for (int i = 0; i < 4; ++i) {
            av0[i] = fmaxf(fmaf(macc[0][i], sc0[i], bias), 0.f);
            av1[i] = fmaxf(fmaf(macc[1][i], sc1[i], bias), 0.f);
        }
        __syncthreads();   // B1: all GEMM reads of x done
        if (ol < 2) {
            if (colok) {
                #pragma unroll
                for (int i = 0; i < 4; ++i) {
                    const int ra = q*4 + i, rb = ra + 16;
                    const short ha = f2bf(av0[i]);
                    xHi[ra*LDX + col] = ha;
                    xLo[ra*LDX + col] = f2bf(av0[i] - bf2f(ha));
                    const short hb = f2bf(av1[i]);
                    xHi[rb*LDX + col] = hb;
                    xLo[rb*LDX + col] = f2bf(av1[i] - bf2f(hb));
                }
            }
        } else {
            // molecule sum: all 32 rows of `col` live in lanes {q*16+ml} of wave w
            float s = 0.f;
            if (colok) {
                #pragma unroll
                for (int i = 0; i < 4; ++i) s += av0[i] + av1[i];
            }
            s += __shfl_xor(s, 16);
            s += __shfl_xor(s, 32);
            if (q == 0 && colok) mv0[col] = s;
            if (t >= 200 && t < DPD) mv0[t] = adducts[mol*4 + (t - 200)];
        }
        __syncthreads();   // B2
    }

    // ---- 3 pred layers on [204] vector, parallelized over all 13 waves ----
    float* pc = mv0;
    float* pn = mv1;
    for (int l = 0; l < 3; ++l) {
        if (t < 816) {
            const int ks = t / 204;          // k-slice 0..3 (51 k's each)
            const int pcol = t - ks * 204;   // output column
            const float* Wl = Wpw + l*DPD*DPD;
            const int k0 = ks * 51;
            float p = 0.f;
            #pragma unroll 3
            for (int k = k0; k < k0 + 51; ++k)
                p = fmaf(pc[k], Wl[k*DPD + pcol], p);   // pc broadcast, Wl coalesced
            ppart[ks*204 + pcol] = p;
        }
        __syncthreads();
        if (t < DPD) {
            const float v = Wpb[l*DPD + t] + ppart[t] + ppart[204 + t]
                          + ppart[408 + t] + ppart[612 + t];
            pn[t] = fmaxf(v, 0.f);
        }
        __syncthreads();
        float* tp = pc; pc = pn; pn = tp;
    }

    // ---- final property head ----
    float v = (t < DPD) ? pc[t] * Wprw[t] : 0.f;
    #pragma unroll
    for (int m = 1; m < 64; m <<= 1) v += __shfl_xor(v, m);
    if (lane == 0) red16[w] = v;
    __syncthreads();
    if (t == 0) {
        float s = Wprb[0];
        #pragma unroll
        for (int ww = 0; ww < 13; ++ww) s += red16[ww];
        out[mol] = s;
    }
}

extern "C" void kernel_launch(void* const* d_in, const int* in_sizes, int n_in,
                              void* d_out, int out_size, void* d_ws, size_t ws_size,
                              hipStream_t stream) {
    const int*   atoms   = (const int*)  d_in[0];
    const float* dist    = (const float*)d_in[1];
    const float* adducts = (const float*)d_in[2];
    const float* embed   = (const float*)d_in[3];
    const float* gamma_t = (const float*)d_in[4];
    const float* Waw     = (const float*)d_in[5];
    const float* Wab     = (const float*)d_in[6];
    const float* Wow     = (const float*)d_in[7];
    const float* Wob     = (const float*)d_in[8];
    const float* Wpw     = (const float*)d_in[9];
    const float* Wpb     = (const float*)d_in[10];
    const float* Wprw    = (const float*)d_in[11];
    const float* Wprb    = (const float*)d_in[12];
    (void)in_sizes; (void)n_in; (void)ws_size; (void)out_size;

    short* W2 = (short*)d_ws;   // 9*WL shorts = ~1.68 MB

    conv_kernel<<<dim3(512), dim3(256), 0, stream>>>(Waw, Wow, W2);
    mgnn_kernel<<<dim3(256), dim3(832), 0, stream>>>(
        atoms, dist, adducts, embed, gamma_t,
        Waw, Wab, Wow, Wob, Wpw, Wpb, Wprw, Wprb,
        W2, (float*)d_out);
}